// Round 1
// baseline (180633.191 us; speedup 1.0000x reference)
//
#include <hip/hip_runtime.h>
#include <hip/hip_bf16.h>
#include <cstdint>
#include <cstddef>

#define TSEQ 2048
#define BB   32
#define UU   512
#define NCOL 1536   // 3U
#define NBLK 256    // scan grid size (one block per 2 hidden units)

// ---------------------------------------------------------------------------
// GEMM: C[m][n] = sum_k A[m][k] * W[k][n] + bias[n]
// fp32, 64x64 block tile, 256 threads, 4x4 micro-tile, K-tile 16.
// M % 64 == 0, N % 64 == 0, K % 16 == 0 (holds: M=65536, N=1536, K=256/512)
// ---------------------------------------------------------------------------
__global__ __launch_bounds__(256)
void gemm_bias(const float* __restrict__ A, const float* __restrict__ W,
               const float* __restrict__ bias, float* __restrict__ C,
               int M, int N, int K)
{
    __shared__ float As[16][68];   // [kk][m] transposed, padded (writes 2-way max)
    __shared__ float Bs[16][64];   // [kk][n]

    const int tid = threadIdx.x;
    const int tx = tid & 15, ty = tid >> 4;
    const int m0 = blockIdx.y * 64, n0 = blockIdx.x * 64;

    float acc[4][4] = {};

    for (int k0 = 0; k0 < K; k0 += 16) {
        // A tile: 64 rows x 16 k, float4 over k, transpose into As
        {
            int r  = tid >> 2;          // 0..63
            int kq = (tid & 3) * 4;     // 0,4,8,12
            float4 av = *(const float4*)&A[(size_t)(m0 + r) * K + k0 + kq];
            As[kq + 0][r] = av.x;
            As[kq + 1][r] = av.y;
            As[kq + 2][r] = av.z;
            As[kq + 3][r] = av.w;
        }
        // B tile: 16 k x 64 n, coalesced float4
        {
            int kk = tid >> 4;          // 0..15
            int n  = (tid & 15) * 4;    // 0..60
            *(float4*)&Bs[kk][n] = *(const float4*)&W[(size_t)(k0 + kk) * N + n0 + n];
        }
        __syncthreads();

        #pragma unroll
        for (int kk = 0; kk < 16; ++kk) {
            float av0 = As[kk][ty * 4 + 0];
            float av1 = As[kk][ty * 4 + 1];
            float av2 = As[kk][ty * 4 + 2];
            float av3 = As[kk][ty * 4 + 3];
            float4 bv = *(const float4*)&Bs[kk][tx * 4];
            acc[0][0] = fmaf(av0, bv.x, acc[0][0]);
            acc[0][1] = fmaf(av0, bv.y, acc[0][1]);
            acc[0][2] = fmaf(av0, bv.z, acc[0][2]);
            acc[0][3] = fmaf(av0, bv.w, acc[0][3]);
            acc[1][0] = fmaf(av1, bv.x, acc[1][0]);
            acc[1][1] = fmaf(av1, bv.y, acc[1][1]);
            acc[1][2] = fmaf(av1, bv.z, acc[1][2]);
            acc[1][3] = fmaf(av1, bv.w, acc[1][3]);
            acc[2][0] = fmaf(av2, bv.x, acc[2][0]);
            acc[2][1] = fmaf(av2, bv.y, acc[2][1]);
            acc[2][2] = fmaf(av2, bv.z, acc[2][2]);
            acc[2][3] = fmaf(av2, bv.w, acc[2][3]);
            acc[3][0] = fmaf(av3, bv.x, acc[3][0]);
            acc[3][1] = fmaf(av3, bv.y, acc[3][1]);
            acc[3][2] = fmaf(av3, bv.z, acc[3][2]);
            acc[3][3] = fmaf(av3, bv.w, acc[3][3]);
        }
        __syncthreads();
    }

    float4 bb = *(const float4*)&bias[n0 + tx * 4];
    #pragma unroll
    for (int i = 0; i < 4; ++i) {
        float4 v;
        v.x = acc[i][0] + bb.x;
        v.y = acc[i][1] + bb.y;
        v.z = acc[i][2] + bb.z;
        v.w = acc[i][3] + bb.w;
        *(float4*)&C[(size_t)(m0 + ty * 4 + i) * N + n0 + tx * 4] = v;
    }
}

// ---------------------------------------------------------------------------
// Persistent GRU scan over T steps. Grid = 256 blocks x 256 threads.
// Block `bid` owns hidden units u0 = 2*bid .. 2*bid+1 (6 rec columns).
// Per step: grid barrier -> stage h (64KB) to LDS -> 192 dot products
// (full K=512) -> gates on 64 threads -> write h_new/out.
// Barrier: flags[bid] = t+1 (release), all threads poll flags[tid] >= t.
// h double-buffered (hA/hB) so one barrier per step suffices.
// ---------------------------------------------------------------------------
__global__ __launch_bounds__(256)
void gru_scan(const float* __restrict__ xproj,   // [B][T][3U]
              const float* __restrict__ rk,      // [U][3U]
              const float* __restrict__ brec,    // [3U]  (bias row 1)
              const float* __restrict__ h0,      // [B][U] initial state
              float* __restrict__ hA,            // [B][U] ping
              float* __restrict__ hB,            // [B][U] pong
              int* flags,                        // [NBLK] zeroed
              float* __restrict__ out,           // [B][T][U]
              float* __restrict__ state_out)     // [B][U]
{
    __shared__ float Rl[6][516];    // rec columns, transposed: Rl[c][k]
    __shared__ float hl[32][516];   // staged h, padded row (stride 516 f32)
    __shared__ float inn[6][33];    // dot results [c][b]
    __shared__ float xp[2][192];    // prefetched xproj slice, double-buffered

    const int tid = threadIdx.x;
    const int bid = blockIdx.x;
    const int u0  = bid * 2;
    const int c   = tid & 7;    // 0..7 (0..5 active for dots)
    const int b8  = tid >> 3;   // 0..31

    // Load this block's 6 recurrent-kernel columns into LDS (once).
    // col(cc) = (cc>>1)*512 + u0 + (cc&1)   [cc = gate*2 + u_local]
    for (int idx = tid; idx < 6 * 512; idx += 256) {
        int cc = idx >> 9;
        int k  = idx & 511;
        Rl[cc][k] = rk[(size_t)k * NCOL + (cc >> 1) * UU + u0 + (cc & 1)];
    }

    // Phase-2 per-thread recurrent biases
    float brz = 0.f, brr = 0.f, brh = 0.f;
    if (tid < 64) {
        int ul = tid >> 5;
        brz = brec[u0 + ul];
        brr = brec[UU + u0 + ul];
        brh = brec[2 * UU + u0 + ul];
    }

    // Prefill xp[0] with t=0 xproj slice (idle-c lanes)
    if (c >= 6) {
        int p  = b8 * 2 + (c - 6);   // 0..63
        int pb = p & 31, pu = p >> 5;
        size_t base = ((size_t)pb * TSEQ + 0) * NCOL + u0 + pu;
        xp[0][      pu * 32 + pb] = xproj[base];
        xp[0][ 64 + pu * 32 + pb] = xproj[base + UU];
        xp[0][128 + pu * 32 + pb] = xproj[base + 2 * UU];
    }
    __syncthreads();

    for (int t = 0; t < TSEQ; ++t) {
        // ---- grid barrier: wait until every block finished step t-1 ----
        if (t > 0) {
            int v;
            do {
                v = __hip_atomic_load(&flags[tid], __ATOMIC_RELAXED,
                                      __HIP_MEMORY_SCOPE_AGENT);
            } while (!__syncthreads_and(v >= t));
            __threadfence();   // acquire: make remote h writes visible
        }

        // ---- stage h (16384 f32) into LDS ----
        const float* hc = (t == 0) ? h0 : ((t & 1) ? hA : hB);
        #pragma unroll
        for (int j = 0; j < 16; ++j) {
            int idx4 = j * 256 + tid;           // 0..4095 float4s
            float4 v = *(const float4*)&hc[idx4 * 4];
            int bb2 = idx4 >> 7;                // f32 index >> 9
            int k   = (idx4 * 4) & 511;
            *(float4*)&hl[bb2][k] = v;
        }
        __syncthreads();

        // ---- phase 1: issue next-step xproj prefetch, then dots ----
        float p0 = 0.f, p1 = 0.f, p2 = 0.f;
        int havePF = 0;
        if (c >= 6 && t + 1 < TSEQ) {
            int p  = b8 * 2 + (c - 6);
            int pb = p & 31, pu = p >> 5;
            size_t base = ((size_t)pb * TSEQ + (t + 1)) * NCOL + u0 + pu;
            p0 = xproj[base];
            p1 = xproj[base + UU];
            p2 = xproj[base + 2 * UU];
            havePF = 1;
        }
        if (c < 6) {
            const float* hrow = hl[b8];
            const float* rrow = Rl[c];
            float acc = 0.f;
            #pragma unroll 4
            for (int k = 0; k < 512; k += 4) {
                float4 hv = *(const float4*)&hrow[k];
                float4 rv = *(const float4*)&rrow[k];
                acc = fmaf(hv.x, rv.x, acc);
                acc = fmaf(hv.y, rv.y, acc);
                acc = fmaf(hv.z, rv.z, acc);
                acc = fmaf(hv.w, rv.w, acc);
            }
            inn[c][b8] = acc;
        }
        if (havePF) {
            int p  = b8 * 2 + (c - 6);
            int pb = p & 31, pu = p >> 5;
            int nb = (t + 1) & 1;
            xp[nb][      pu * 32 + pb] = p0;
            xp[nb][ 64 + pu * 32 + pb] = p1;
            xp[nb][128 + pu * 32 + pb] = p2;
        }
        __syncthreads();

        // ---- phase 2: gates + state update (64 threads: 32 b x 2 u) ----
        if (tid < 64) {
            int bb2 = tid & 31, ul = tid >> 5;
            int ug  = u0 + ul;
            float iz = inn[ul][bb2] + brz;
            float ir = inn[2 + ul][bb2] + brr;
            float ih = inn[4 + ul][bb2] + brh;
            const float* x = xp[t & 1];
            float xz = x[      ul * 32 + bb2];
            float xr = x[ 64 + ul * 32 + bb2];
            float xh = x[128 + ul * 32 + bb2];
            float z  = 1.f / (1.f + expf(-(xz + iz)));
            float r  = 1.f / (1.f + expf(-(xr + ir)));
            float hh = tanhf(xh + r * ih);           // reset_after form
            float hold = hl[bb2][ug];
            float hnew = z * hold + (1.f - z) * hh;
            float* hn = (t & 1) ? hB : hA;
            hn[bb2 * UU + ug] = hnew;
            out[((size_t)bb2 * TSEQ + t) * UU + ug] = hnew;
            if (t == TSEQ - 1) state_out[bb2 * UU + ug] = hnew;
        }
        __syncthreads();
        __threadfence();   // release: flush h_new before signaling
        if (tid == 0)
            __hip_atomic_store(&flags[bid], t + 1, __ATOMIC_RELAXED,
                               __HIP_MEMORY_SCOPE_AGENT);
    }
}

// ---------------------------------------------------------------------------
extern "C" void kernel_launch(void* const* d_in, const int* in_sizes, int n_in,
                              void* d_out, int out_size, void* d_ws, size_t ws_size,
                              hipStream_t stream)
{
    const float* x      = (const float*)d_in[0];  // [B,T,D]
    const float* hidden = (const float*)d_in[1];  // [B,U] (zeros)
    const float* k1     = (const float*)d_in[2];  // [D,3U]
    const float* rk1    = (const float*)d_in[3];  // [U,3U]
    const float* b1     = (const float*)d_in[4];  // [2,3U]
    const float* k2     = (const float*)d_in[5];  // [U,3U]
    const float* rk2    = (const float*)d_in[6];  // [U,3U]
    const float* b2     = (const float*)d_in[7];  // [2,3U]

    const int M = BB * TSEQ;                      // 65536
    const size_t XPROJ_ELEMS = (size_t)M * NCOL;  // 100,663,296 f32 (~402.6 MB)

    float* xproj  = (float*)d_ws;
    float* hA     = xproj + XPROJ_ELEMS;
    float* hB     = hA + BB * UU;
    int*   flags1 = (int*)(hB + BB * UU);
    int*   flags2 = flags1 + NBLK;

    size_t need = (XPROJ_ELEMS + 2 * (size_t)BB * UU) * sizeof(float)
                + 2 * NBLK * sizeof(int);
    if (ws_size < need) return;   // loud failure (output stays poisoned)

    float* out    = (float*)d_out;
    float* state1 = out + (size_t)BB * TSEQ * UU;
    float* state2 = state1 + BB * UU;

    hipMemsetAsync(flags1, 0, 2 * NBLK * sizeof(int), stream);

    dim3 ggrid(NCOL / 64, M / 64);   // (24, 1024)

    // Layer 1
    gemm_bias<<<ggrid, 256, 0, stream>>>(x, k1, b1, xproj, M, NCOL, 256);
    gru_scan<<<NBLK, 256, 0, stream>>>(xproj, rk1, b1 + NCOL, hidden,
                                       hA, hB, flags1, out, state1);
    // Layer 2 (input = out1 stored in d_out; h0 = `hidden` again, per source)
    gemm_bias<<<ggrid, 256, 0, stream>>>(out, k2, b2, xproj, M, NCOL, 512);
    gru_scan<<<NBLK, 256, 0, stream>>>(xproj, rk2, b2 + NCOL, hidden,
                                       hA, hB, flags2, out, state2);
}

// Round 2
// 94046.777 us; speedup vs baseline: 1.9207x; 1.9207x over previous
//
#include <hip/hip_runtime.h>
#include <hip/hip_bf16.h>
#include <cstdint>
#include <cstddef>

#define TSEQ 2048
#define BB   32
#define UU   512
#define NCOL 1536   // 3U
#define NBLK 256    // scan grid size (one block per 2 hidden units)

// ---------------------------------------------------------------------------
// GEMM: C[m][n] = sum_k A[m][k] * W[k][n] + bias[n]
// fp32, 64x64 block tile, 256 threads, 4x4 micro-tile, K-tile 16.
// ---------------------------------------------------------------------------
__global__ __launch_bounds__(256)
void gemm_bias(const float* __restrict__ A, const float* __restrict__ W,
               const float* __restrict__ bias, float* __restrict__ C,
               int M, int N, int K)
{
    __shared__ float As[16][68];
    __shared__ float Bs[16][64];

    const int tid = threadIdx.x;
    const int tx = tid & 15, ty = tid >> 4;
    const int m0 = blockIdx.y * 64, n0 = blockIdx.x * 64;

    float acc[4][4] = {};

    for (int k0 = 0; k0 < K; k0 += 16) {
        {
            int r  = tid >> 2;
            int kq = (tid & 3) * 4;
            float4 av = *(const float4*)&A[(size_t)(m0 + r) * K + k0 + kq];
            As[kq + 0][r] = av.x;
            As[kq + 1][r] = av.y;
            As[kq + 2][r] = av.z;
            As[kq + 3][r] = av.w;
        }
        {
            int kk = tid >> 4;
            int n  = (tid & 15) * 4;
            *(float4*)&Bs[kk][n] = *(const float4*)&W[(size_t)(k0 + kk) * N + n0 + n];
        }
        __syncthreads();

        #pragma unroll
        for (int kk = 0; kk < 16; ++kk) {
            float av0 = As[kk][ty * 4 + 0];
            float av1 = As[kk][ty * 4 + 1];
            float av2 = As[kk][ty * 4 + 2];
            float av3 = As[kk][ty * 4 + 3];
            float4 bv = *(const float4*)&Bs[kk][tx * 4];
            acc[0][0] = fmaf(av0, bv.x, acc[0][0]);
            acc[0][1] = fmaf(av0, bv.y, acc[0][1]);
            acc[0][2] = fmaf(av0, bv.z, acc[0][2]);
            acc[0][3] = fmaf(av0, bv.w, acc[0][3]);
            acc[1][0] = fmaf(av1, bv.x, acc[1][0]);
            acc[1][1] = fmaf(av1, bv.y, acc[1][1]);
            acc[1][2] = fmaf(av1, bv.z, acc[1][2]);
            acc[1][3] = fmaf(av1, bv.w, acc[1][3]);
            acc[2][0] = fmaf(av2, bv.x, acc[2][0]);
            acc[2][1] = fmaf(av2, bv.y, acc[2][1]);
            acc[2][2] = fmaf(av2, bv.z, acc[2][2]);
            acc[2][3] = fmaf(av2, bv.w, acc[2][3]);
            acc[3][0] = fmaf(av3, bv.x, acc[3][0]);
            acc[3][1] = fmaf(av3, bv.y, acc[3][1]);
            acc[3][2] = fmaf(av3, bv.z, acc[3][2]);
            acc[3][3] = fmaf(av3, bv.w, acc[3][3]);
        }
        __syncthreads();
    }

    float4 bb = *(const float4*)&bias[n0 + tx * 4];
    #pragma unroll
    for (int i = 0; i < 4; ++i) {
        float4 v;
        v.x = acc[i][0] + bb.x;
        v.y = acc[i][1] + bb.y;
        v.z = acc[i][2] + bb.z;
        v.w = acc[i][3] + bb.w;
        *(float4*)&C[(size_t)(m0 + ty * 4 + i) * N + n0 + tx * 4] = v;
    }
}

// ---------------------------------------------------------------------------
// Persistent GRU scan. Grid = 256 blocks x 256 threads, block owns 2 units.
// Barrier v2: wave 0 only polls (lane l spins on flags[4l..4l+3]); one
// __syncthreads() proves all 256 flags >= t; single acquire fence per block.
// Release: one RELEASE atomic store by tid 0 after __syncthreads().
// ---------------------------------------------------------------------------
__global__ __launch_bounds__(256)
void gru_scan(const float* __restrict__ xproj,   // [B][T][3U]
              const float* __restrict__ rk,      // [U][3U]
              const float* __restrict__ brec,    // [3U]
              const float* __restrict__ h0,      // [B][U]
              float* __restrict__ hA,            // ping
              float* __restrict__ hB,            // pong
              int* flags,                        // [NBLK] zeroed
              float* __restrict__ out,           // [B][T][U]
              float* __restrict__ state_out)     // [B][U]
{
    __shared__ float Rl[6][516];
    __shared__ float hl[32][516];
    __shared__ float inn[6][33];
    __shared__ float xp[2][192];

    const int tid = threadIdx.x;
    const int bid = blockIdx.x;
    const int u0  = bid * 2;
    const int c   = tid & 7;
    const int b8  = tid >> 3;

    for (int idx = tid; idx < 6 * 512; idx += 256) {
        int cc = idx >> 9;
        int k  = idx & 511;
        Rl[cc][k] = rk[(size_t)k * NCOL + (cc >> 1) * UU + u0 + (cc & 1)];
    }

    float brz = 0.f, brr = 0.f, brh = 0.f;
    if (tid < 64) {
        int ul = tid >> 5;
        brz = brec[u0 + ul];
        brr = brec[UU + u0 + ul];
        brh = brec[2 * UU + u0 + ul];
    }

    if (c >= 6) {
        int p  = b8 * 2 + (c - 6);
        int pb = p & 31, pu = p >> 5;
        size_t base = ((size_t)pb * TSEQ + 0) * NCOL + u0 + pu;
        xp[0][      pu * 32 + pb] = xproj[base];
        xp[0][ 64 + pu * 32 + pb] = xproj[base + UU];
        xp[0][128 + pu * 32 + pb] = xproj[base + 2 * UU];
    }
    __syncthreads();

    for (int t = 0; t < TSEQ; ++t) {
        // ---- grid barrier: wave 0 polls, 4 flags per lane ----
        if (t > 0) {
            if (tid < 64) {
                const int base = tid * 4;
                for (;;) {
                    int a = __hip_atomic_load(&flags[base + 0], __ATOMIC_RELAXED,
                                              __HIP_MEMORY_SCOPE_AGENT);
                    int b = __hip_atomic_load(&flags[base + 1], __ATOMIC_RELAXED,
                                              __HIP_MEMORY_SCOPE_AGENT);
                    int cc = __hip_atomic_load(&flags[base + 2], __ATOMIC_RELAXED,
                                               __HIP_MEMORY_SCOPE_AGENT);
                    int d = __hip_atomic_load(&flags[base + 3], __ATOMIC_RELAXED,
                                              __HIP_MEMORY_SCOPE_AGENT);
                    if (min(min(a, b), min(cc, d)) >= t) break;
                    __builtin_amdgcn_s_sleep(1);
                }
            }
            __syncthreads();
            __builtin_amdgcn_fence(__ATOMIC_ACQUIRE, "agent");
        }

        // ---- stage h (16384 f32) into LDS ----
        const float* hc = (t == 0) ? h0 : ((t & 1) ? hA : hB);
        #pragma unroll
        for (int j = 0; j < 16; ++j) {
            int idx4 = j * 256 + tid;
            float4 v = *(const float4*)&hc[idx4 * 4];
            int bb2 = idx4 >> 7;
            int k   = (idx4 * 4) & 511;
            *(float4*)&hl[bb2][k] = v;
        }
        __syncthreads();

        // ---- phase 1: prefetch next xproj slice + 192 dot products ----
        float p0 = 0.f, p1 = 0.f, p2 = 0.f;
        int havePF = 0;
        if (c >= 6 && t + 1 < TSEQ) {
            int p  = b8 * 2 + (c - 6);
            int pb = p & 31, pu = p >> 5;
            size_t base = ((size_t)pb * TSEQ + (t + 1)) * NCOL + u0 + pu;
            p0 = xproj[base];
            p1 = xproj[base + UU];
            p2 = xproj[base + 2 * UU];
            havePF = 1;
        }
        if (c < 6) {
            const float* hrow = hl[b8];
            const float* rrow = Rl[c];
            float acc = 0.f;
            #pragma unroll 4
            for (int k = 0; k < 512; k += 4) {
                float4 hv = *(const float4*)&hrow[k];
                float4 rv = *(const float4*)&rrow[k];
                acc = fmaf(hv.x, rv.x, acc);
                acc = fmaf(hv.y, rv.y, acc);
                acc = fmaf(hv.z, rv.z, acc);
                acc = fmaf(hv.w, rv.w, acc);
            }
            inn[c][b8] = acc;
        }
        if (havePF) {
            int p  = b8 * 2 + (c - 6);
            int pb = p & 31, pu = p >> 5;
            int nb = (t + 1) & 1;
            xp[nb][      pu * 32 + pb] = p0;
            xp[nb][ 64 + pu * 32 + pb] = p1;
            xp[nb][128 + pu * 32 + pb] = p2;
        }
        __syncthreads();

        // ---- phase 2: gates + state update (64 threads) ----
        if (tid < 64) {
            int bb2 = tid & 31, ul = tid >> 5;
            int ug  = u0 + ul;
            float iz = inn[ul][bb2] + brz;
            float ir = inn[2 + ul][bb2] + brr;
            float ih = inn[4 + ul][bb2] + brh;
            const float* x = xp[t & 1];
            float xz = x[      ul * 32 + bb2];
            float xr = x[ 64 + ul * 32 + bb2];
            float xh = x[128 + ul * 32 + bb2];
            float z  = 1.f / (1.f + expf(-(xz + iz)));
            float r  = 1.f / (1.f + expf(-(xr + ir)));
            float hh = tanhf(xh + r * ih);
            float hold = hl[bb2][ug];
            float hnew = z * hold + (1.f - z) * hh;
            float* hn = (t & 1) ? hB : hA;
            hn[bb2 * UU + ug] = hnew;
            out[((size_t)bb2 * TSEQ + t) * UU + ug] = hnew;
            if (t == TSEQ - 1) state_out[bb2 * UU + ug] = hnew;
        }
        __syncthreads();   // drains phase-2 global stores (waitcnt before barrier)
        if (tid == 0)
            __hip_atomic_store(&flags[bid], t + 1, __ATOMIC_RELEASE,
                               __HIP_MEMORY_SCOPE_AGENT);
    }
}

// ---------------------------------------------------------------------------
extern "C" void kernel_launch(void* const* d_in, const int* in_sizes, int n_in,
                              void* d_out, int out_size, void* d_ws, size_t ws_size,
                              hipStream_t stream)
{
    const float* x      = (const float*)d_in[0];
    const float* hidden = (const float*)d_in[1];
    const float* k1     = (const float*)d_in[2];
    const float* rk1    = (const float*)d_in[3];
    const float* b1     = (const float*)d_in[4];
    const float* k2     = (const float*)d_in[5];
    const float* rk2    = (const float*)d_in[6];
    const float* b2     = (const float*)d_in[7];

    const int M = BB * TSEQ;                      // 65536
    const size_t XPROJ_ELEMS = (size_t)M * NCOL;

    float* xproj  = (float*)d_ws;
    float* hA     = xproj + XPROJ_ELEMS;
    float* hB     = hA + BB * UU;
    int*   flags1 = (int*)(hB + BB * UU);
    int*   flags2 = flags1 + NBLK;

    size_t need = (XPROJ_ELEMS + 2 * (size_t)BB * UU) * sizeof(float)
                + 2 * NBLK * sizeof(int);
    if (ws_size < need) return;

    float* out    = (float*)d_out;
    float* state1 = out + (size_t)BB * TSEQ * UU;
    float* state2 = state1 + BB * UU;

    hipMemsetAsync(flags1, 0, 2 * NBLK * sizeof(int), stream);

    dim3 ggrid(NCOL / 64, M / 64);

    gemm_bias<<<ggrid, 256, 0, stream>>>(x, k1, b1, xproj, M, NCOL, 256);
    gru_scan<<<NBLK, 256, 0, stream>>>(xproj, rk1, b1 + NCOL, hidden,
                                       hA, hB, flags1, out, state1);
    gemm_bias<<<ggrid, 256, 0, stream>>>(out, k2, b2, xproj, M, NCOL, 512);
    gru_scan<<<NBLK, 256, 0, stream>>>(xproj, rk2, b2 + NCOL, hidden,
                                       hA, hB, flags2, out, state2);
}

// Round 3
// 18496.434 us; speedup vs baseline: 9.7658x; 5.0846x over previous
//
#include <hip/hip_runtime.h>
#include <hip/hip_bf16.h>
#include <cstdint>
#include <cstddef>

#define TSEQ 2048
#define BB   32
#define UU   512
#define NCOL 1536   // 3U
#define NSB  256    // scan blocks (8 groups x 32)
#define GBLK 32     // blocks per group

// ---------------------------------------------------------------------------
// GEMM: C[m][n] = sum_k A[m][k]*W[k][n] + bias[n]  (fp32, 64x64 tile)
// ---------------------------------------------------------------------------
__global__ __launch_bounds__(256)
void gemm_bias(const float* __restrict__ A, const float* __restrict__ W,
               const float* __restrict__ bias, float* __restrict__ C,
               int M, int N, int K)
{
    __shared__ float As[16][68];
    __shared__ float Bs[16][64];

    const int tid = threadIdx.x;
    const int tx = tid & 15, ty = tid >> 4;
    const int m0 = blockIdx.y * 64, n0 = blockIdx.x * 64;

    float acc[4][4] = {};

    for (int k0 = 0; k0 < K; k0 += 16) {
        {
            int r  = tid >> 2;
            int kq = (tid & 3) * 4;
            float4 av = *(const float4*)&A[(size_t)(m0 + r) * K + k0 + kq];
            As[kq + 0][r] = av.x;
            As[kq + 1][r] = av.y;
            As[kq + 2][r] = av.z;
            As[kq + 3][r] = av.w;
        }
        {
            int kk = tid >> 4;
            int n  = (tid & 15) * 4;
            *(float4*)&Bs[kk][n] = *(const float4*)&W[(size_t)(k0 + kk) * N + n0 + n];
        }
        __syncthreads();

        #pragma unroll
        for (int kk = 0; kk < 16; ++kk) {
            float av0 = As[kk][ty * 4 + 0];
            float av1 = As[kk][ty * 4 + 1];
            float av2 = As[kk][ty * 4 + 2];
            float av3 = As[kk][ty * 4 + 3];
            float4 bv = *(const float4*)&Bs[kk][tx * 4];
            acc[0][0] = fmaf(av0, bv.x, acc[0][0]);
            acc[0][1] = fmaf(av0, bv.y, acc[0][1]);
            acc[0][2] = fmaf(av0, bv.z, acc[0][2]);
            acc[0][3] = fmaf(av0, bv.w, acc[0][3]);
            acc[1][0] = fmaf(av1, bv.x, acc[1][0]);
            acc[1][1] = fmaf(av1, bv.y, acc[1][1]);
            acc[1][2] = fmaf(av1, bv.z, acc[1][2]);
            acc[1][3] = fmaf(av1, bv.w, acc[1][3]);
            acc[2][0] = fmaf(av2, bv.x, acc[2][0]);
            acc[2][1] = fmaf(av2, bv.y, acc[2][1]);
            acc[2][2] = fmaf(av2, bv.z, acc[2][2]);
            acc[2][3] = fmaf(av2, bv.w, acc[2][3]);
            acc[3][0] = fmaf(av3, bv.x, acc[3][0]);
            acc[3][1] = fmaf(av3, bv.y, acc[3][1]);
            acc[3][2] = fmaf(av3, bv.z, acc[3][2]);
            acc[3][3] = fmaf(av3, bv.w, acc[3][3]);
        }
        __syncthreads();
    }

    float4 bb = *(const float4*)&bias[n0 + tx * 4];
    #pragma unroll
    for (int i = 0; i < 4; ++i) {
        float4 v;
        v.x = acc[i][0] + bb.x;
        v.y = acc[i][1] + bb.y;
        v.z = acc[i][2] + bb.z;
        v.w = acc[i][3] + bb.w;
        *(float4*)&C[(size_t)(m0 + ty * 4 + i) * N + n0 + tx * 4] = v;
    }
}

// ---------------------------------------------------------------------------
// GRU scan v3: 8 independent groups (4 batch rows each) x 32 blocks
// (16 units each). 512 threads/block, 1 block/CU. Recurrent weights live in
// registers (thread (col,k-slice) owns 64 f32). h state exchanged via
// RELAXED AGENT atomics (cache-bypassing, NO fences): __syncthreads() drains
// vmcnt before the flag store, so h-stores reach the coherence point before
// the flag is visible; consumers bypass stale caches by construction.
// ---------------------------------------------------------------------------
__global__ __launch_bounds__(512, 2)
void gru_scan(const float* __restrict__ xproj,   // [B][T][3U]
              const float* __restrict__ rk,      // [U][3U]
              const float* __restrict__ brec,    // [3U]
              const float* __restrict__ h0,      // [B][U]
              float* hA, float* hB,              // ping/pong [B][U]
              int* flags,                        // [8*32] zeroed
              float* __restrict__ out,           // [B][T][U]
              float* __restrict__ state_out)     // [B][U]
{
    __shared__ __align__(16) float hl[4][512];   // group's h, XOR-swizzled
    __shared__ float inn[48][4];                 // dot results [col][row]
    __shared__ float xp[2][192];                 // xproj slices, dbuf

    const int tid  = threadIdx.x;
    const int bid  = blockIdx.x;
    const int g    = bid & 7;          // group (round-robin -> XCD-aligned)
    const int slot = bid >> 3;         // 0..31
    const int u0   = slot * 16;        // owned units
    const int b0   = g * 4;            // owned batch rows
    const int cl   = tid >> 3;         // 0..63 (0..47 = real cols)
    const int j    = tid & 7;          // k-slice (64 wide)
    const int j2   = j << 2;           // LDS swizzle constant

    // ---- recurrent weights -> registers (once) ----
    float wreg[64];
    if (cl < 48) {
        const int col = (cl >> 4) * UU + u0 + (cl & 15);
        const float* base = rk + (size_t)(j * 64) * NCOL + col;
        #pragma unroll
        for (int q = 0; q < 64; ++q) wreg[q] = base[(size_t)q * NCOL];
    }

    // ---- phase-2 biases ----
    float brz = 0.f, brr = 0.f, brh = 0.f;
    if (tid < 64) {
        int iu = tid & 15;
        brz = brec[u0 + iu];
        brr = brec[UU + u0 + iu];
        brh = brec[2 * UU + u0 + iu];
    }

    // ---- prefill xp[0] (t=0 slice), threads 384..511 ----
    if (tid >= 384) {
        int p = tid - 384;
        {
            int c = p >> 2, b = p & 3;
            xp[0][p] = xproj[((size_t)(b0 + b) * TSEQ + 0) * NCOL
                             + (c >> 4) * UU + u0 + (c & 15)];
        }
        int p2 = p + 128;
        if (p2 < 192) {
            int c = p2 >> 2, b = p2 & 3;
            xp[0][p2] = xproj[((size_t)(b0 + b) * TSEQ + 0) * NCOL
                              + (c >> 4) * UU + u0 + (c & 15)];
        }
    }

    for (int t = 0; t < TSEQ; ++t) {
        // ---- group barrier: wave 0 polls its 32 flags (relaxed, no fence) ----
        if (t > 0) {
            if (tid < 64) {
                int* f = flags + g * GBLK + (tid & 31);
                for (;;) {
                    int v = __hip_atomic_load(f, __ATOMIC_RELAXED,
                                              __HIP_MEMORY_SCOPE_AGENT);
                    if (__all(v >= t)) break;
                    __builtin_amdgcn_s_sleep(1);
                }
            }
        }
        __syncthreads();

        // ---- stage group h (4x512) into LDS, XOR-swizzled ----
        const float* hc = (t & 1) ? hA : hB;   // written at t-1
        #pragma unroll
        for (int i = 0; i < 4; ++i) {
            int idx = i * 512 + tid;           // 0..2047
            int row = idx >> 9, k = idx & 511;
            float v;
            if (t == 0) {
                v = h0[(size_t)(b0 + row) * UU + k];
            } else {
                v = __int_as_float(__hip_atomic_load(
                        (const int*)&hc[(size_t)(b0 + row) * UU + k],
                        __ATOMIC_RELAXED, __HIP_MEMORY_SCOPE_AGENT));
            }
            int pos = k ^ (((k >> 6) & 7) << 2);
            hl[row][pos] = v;
        }
        __syncthreads();

        // ---- dots (threads cl<48) / xproj prefetch (threads >=384) ----
        if (cl < 48) {
            const int kb = j * 64;
            float a0 = 0.f, a1 = 0.f, a2 = 0.f, a3 = 0.f;
            #pragma unroll
            for (int q0 = 0; q0 < 64; q0 += 4) {
                int p = kb + (q0 ^ j2);
                float4 h0v = *(const float4*)&hl[0][p];
                float4 h1v = *(const float4*)&hl[1][p];
                float4 h2v = *(const float4*)&hl[2][p];
                float4 h3v = *(const float4*)&hl[3][p];
                a0 = fmaf(wreg[q0+0], h0v.x, a0); a1 = fmaf(wreg[q0+0], h1v.x, a1);
                a2 = fmaf(wreg[q0+0], h2v.x, a2); a3 = fmaf(wreg[q0+0], h3v.x, a3);
                a0 = fmaf(wreg[q0+1], h0v.y, a0); a1 = fmaf(wreg[q0+1], h1v.y, a1);
                a2 = fmaf(wreg[q0+1], h2v.y, a2); a3 = fmaf(wreg[q0+1], h3v.y, a3);
                a0 = fmaf(wreg[q0+2], h0v.z, a0); a1 = fmaf(wreg[q0+2], h1v.z, a1);
                a2 = fmaf(wreg[q0+2], h2v.z, a2); a3 = fmaf(wreg[q0+2], h3v.z, a3);
                a0 = fmaf(wreg[q0+3], h0v.w, a0); a1 = fmaf(wreg[q0+3], h1v.w, a1);
                a2 = fmaf(wreg[q0+3], h2v.w, a2); a3 = fmaf(wreg[q0+3], h3v.w, a3);
            }
            #pragma unroll
            for (int m = 1; m < 8; m <<= 1) {
                a0 += __shfl_xor(a0, m);
                a1 += __shfl_xor(a1, m);
                a2 += __shfl_xor(a2, m);
                a3 += __shfl_xor(a3, m);
            }
            if (j == 0) {
                inn[cl][0] = a0; inn[cl][1] = a1;
                inn[cl][2] = a2; inn[cl][3] = a3;
            }
        } else if (tid >= 384 && t + 1 < TSEQ) {
            int nb = (t + 1) & 1;
            int p = tid - 384;
            {
                int c = p >> 2, b = p & 3;
                xp[nb][p] = xproj[((size_t)(b0 + b) * TSEQ + (t + 1)) * NCOL
                                  + (c >> 4) * UU + u0 + (c & 15)];
            }
            int p2 = p + 128;
            if (p2 < 192) {
                int c = p2 >> 2, b = p2 & 3;
                xp[nb][p2] = xproj[((size_t)(b0 + b) * TSEQ + (t + 1)) * NCOL
                                   + (c >> 4) * UU + u0 + (c & 15)];
            }
        }
        __syncthreads();

        // ---- gates + state update (64 threads: 4 rows x 16 units) ----
        if (tid < 64) {
            int bl = tid >> 4, iu = tid & 15;
            int ug = u0 + iu;
            float iz = inn[iu][bl]      + brz;
            float ir = inn[16 + iu][bl] + brr;
            float ih = inn[32 + iu][bl] + brh;
            const float* x = xp[t & 1];
            float xz = x[iu * 4 + bl];
            float xr = x[(16 + iu) * 4 + bl];
            float xh = x[(32 + iu) * 4 + bl];
            float z  = 1.f / (1.f + expf(-(xz + iz)));
            float r  = 1.f / (1.f + expf(-(xr + ir)));
            float hh = tanhf(xh + r * ih);
            int pos = ug ^ (((ug >> 6) & 7) << 2);
            float hold = hl[bl][pos];
            float hnew = z * hold + (1.f - z) * hh;
            float* hn = (t & 1) ? hB : hA;
            __hip_atomic_store((int*)&hn[(size_t)(b0 + bl) * UU + ug],
                               __float_as_int(hnew),
                               __ATOMIC_RELAXED, __HIP_MEMORY_SCOPE_AGENT);
            out[((size_t)(b0 + bl) * TSEQ + t) * UU + ug] = hnew;
            if (t == TSEQ - 1) state_out[(size_t)(b0 + bl) * UU + ug] = hnew;
        }
        __syncthreads();   // drains vmcnt(0): h-stores at MALL before flag
        if (tid == 0)
            __hip_atomic_store(&flags[g * GBLK + slot], t + 1,
                               __ATOMIC_RELAXED, __HIP_MEMORY_SCOPE_AGENT);
    }
}

// ---------------------------------------------------------------------------
extern "C" void kernel_launch(void* const* d_in, const int* in_sizes, int n_in,
                              void* d_out, int out_size, void* d_ws, size_t ws_size,
                              hipStream_t stream)
{
    const float* x      = (const float*)d_in[0];
    const float* hidden = (const float*)d_in[1];
    const float* k1     = (const float*)d_in[2];
    const float* rk1    = (const float*)d_in[3];
    const float* b1     = (const float*)d_in[4];
    const float* k2     = (const float*)d_in[5];
    const float* rk2    = (const float*)d_in[6];
    const float* b2     = (const float*)d_in[7];

    const int M = BB * TSEQ;                      // 65536
    const size_t XPROJ_ELEMS = (size_t)M * NCOL;

    float* xproj  = (float*)d_ws;
    float* hA     = xproj + XPROJ_ELEMS;
    float* hB     = hA + BB * UU;
    int*   flags1 = (int*)(hB + BB * UU);
    int*   flags2 = flags1 + NSB;

    size_t need = (XPROJ_ELEMS + 2 * (size_t)BB * UU) * sizeof(float)
                + 2 * NSB * sizeof(int);
    if (ws_size < need) return;

    float* out    = (float*)d_out;
    float* state1 = out + (size_t)BB * TSEQ * UU;
    float* state2 = state1 + BB * UU;

    hipMemsetAsync(flags1, 0, 2 * NSB * sizeof(int), stream);

    dim3 ggrid(NCOL / 64, M / 64);

    gemm_bias<<<ggrid, 256, 0, stream>>>(x, k1, b1, xproj, M, NCOL, 256);
    gru_scan<<<NSB, 512, 0, stream>>>(xproj, rk1, b1 + NCOL, hidden,
                                      hA, hB, flags1, out, state1);
    gemm_bias<<<ggrid, 256, 0, stream>>>(out, k2, b2, xproj, M, NCOL, 512);
    gru_scan<<<NSB, 512, 0, stream>>>(xproj, rk2, b2 + NCOL, hidden,
                                      hA, hB, flags2, out, state2);
}